// Round 25
// baseline (143.571 us; speedup 1.0000x reference)
//
#include <hip/hip_runtime.h>
#include <math.h>

// ---- problem constants ----
#define TOK    50176      // 2*8*56*56 tokens
#define CH     128
#define NWIN   128        // B * 64 windows
#define NTOK   392        // 8*7*7 tokens per window
#define NHEADS 4
#define QSCALE 0.17677669529663687f   // 32^-0.5
#define LNEPS  1e-3f

typedef unsigned short u16;
typedef unsigned int   u32;
typedef u16   u16x4  __attribute__((ext_vector_type(4)));
typedef u16   u16x8  __attribute__((ext_vector_type(8)));
typedef short s16x8  __attribute__((ext_vector_type(8)));
typedef float f32x4  __attribute__((ext_vector_type(4)));

__device__ __forceinline__ float bf2f(u16 u) {
    return __uint_as_float(((u32)u) << 16);
}
__device__ __forceinline__ u16 f2bf(float f) {
    u32 u = __float_as_uint(f);
    return (u16)((u + 0x7fffu + ((u >> 16) & 1u)) >> 16);
}
__device__ __forceinline__ f32x4 mfma16(s16x8 a, s16x8 b, f32x4 c) {
    return __builtin_amdgcn_mfma_f32_16x16x32_bf16(a, b, c, 0, 0, 0);
}

// token m in window layout -> flat token index in original layout (+3 roll)
__device__ __forceinline__ int src_index(int m) {
    int b = m / NTOK, t = m - b * NTOK;
    int batch = b >> 6, wIdx = b & 63;
    int bh = wIdx >> 3, bw = wIdx & 7;
    int d = t / 49, rem = t - d * 49;
    int h7 = rem / 7, w7 = rem - h7 * 7;
    int h = bh * 7 + h7 + 3; if (h >= 56) h -= 56;
    int w = bw * 7 + w7 + 3; if (w >= 56) w -= 56;
    return ((batch * 8 + d) * 56 + h) * 56 + w;
}

// ---- batched weight transpose + f32->bf16: all 4 weights, one launch ----
__global__ __launch_bounds__(256) void convT_all(
    const float* __restrict__ qkv_w, const float* __restrict__ proj_w,
    const float* __restrict__ fc1_w, const float* __restrict__ fc2_w,
    u16* __restrict__ qkvT, u16* __restrict__ projT,
    u16* __restrict__ fc1T, u16* __restrict__ fc2T)
{
    const float* src; u16* dst; int K, N, scaleN;
    switch (blockIdx.z) {
    case 0:  src = qkv_w;  dst = qkvT;  K = 128; N = 384; scaleN = 128; break;
    case 1:  src = proj_w; dst = projT; K = 128; N = 128; scaleN = 0;   break;
    case 2:  src = fc1_w;  dst = fc1T;  K = 128; N = 512; scaleN = 0;   break;
    default: src = fc2_w;  dst = fc2T;  K = 512; N = 128; scaleN = 0;   break;
    }
    int n0 = blockIdx.x * 32, k0 = blockIdx.y * 32;
    if (n0 >= N || k0 >= K) return;
    __shared__ float t[32][33];
    int tx = threadIdx.x & 31, ty = threadIdx.x >> 5;   // ty 0..7
    #pragma unroll
    for (int r = 0; r < 4; ++r)
        t[ty + r * 8][tx] = src[(size_t)(k0 + ty + r * 8) * N + n0 + tx];
    __syncthreads();
    #pragma unroll
    for (int r = 0; r < 4; ++r) {
        int n = n0 + ty + r * 8;
        float sc = (n < scaleN) ? QSCALE : 1.f;
        dst[(size_t)n * K + k0 + tx] = f2bf(t[tx][ty + r * 8] * sc);
    }
}

// ---- fused LN1 + qkv GEMM, one block per 64-token tile, loops 3 n-tiles ----
__global__ __launch_bounds__(512, 6) void qkv_ln(
    const float* __restrict__ x, const u16* __restrict__ W,
    const float* __restrict__ bias, u16* __restrict__ outp,
    const float* __restrict__ lng, const float* __restrict__ lnb)
{
    __shared__ u16 As[4][64][32];    // 16 KB
    __shared__ u16 Bs[4][128][32];   // 32 KB

    int tid = threadIdx.x, l = tid & 63;
    int c16 = l & 15, g4 = l >> 4;
    int m0 = blockIdx.x * 64;
    int w = tid >> 6, wm = w & 3, wn = w >> 2;
    int srow = tid >> 4, sc8 = tid & 15;

    u16x8 wv[4];
    #pragma unroll
    for (int p = 0; p < 4; ++p)
        wv[p] = *(const u16x8*)&W[(size_t)(srow + p * 32) * 128 + sc8 * 8];

    #pragma unroll
    for (int p = 0; p < 2; ++p) {
        int row = srow + p * 32;
        int src = src_index(m0 + row);
        f32x4 x0 = *(const f32x4*)&x[(size_t)src * CH + sc8 * 8];
        f32x4 x1 = *(const f32x4*)&x[(size_t)src * CH + sc8 * 8 + 4];
        float s = ((x0[0] + x0[1]) + (x0[2] + x0[3]))
                + ((x1[0] + x1[1]) + (x1[2] + x1[3]));
        float q = ((x0[0]*x0[0] + x0[1]*x0[1]) + (x0[2]*x0[2] + x0[3]*x0[3]))
                + ((x1[0]*x1[0] + x1[1]*x1[1]) + (x1[2]*x1[2] + x1[3]*x1[3]));
        #pragma unroll
        for (int o = 1; o <= 8; o <<= 1) {
            s += __shfl_xor(s, o);
            q += __shfl_xor(q, o);
        }
        float mean = s * (1.f / CH);
        float var  = q * (1.f / CH) - mean * mean;
        float rstd = rsqrtf(var + LNEPS);
        u16x8 av;
        #pragma unroll
        for (int i = 0; i < 4; ++i)
            av[i] = f2bf((x0[i] - mean) * rstd * lng[sc8 * 8 + i] + lnb[sc8 * 8 + i]);
        #pragma unroll
        for (int i = 0; i < 4; ++i)
            av[4 + i] = f2bf((x1[i] - mean) * rstd * lng[sc8 * 8 + 4 + i] + lnb[sc8 * 8 + 4 + i]);
        *(u16x8*)&As[sc8 >> 2][row][(sc8 & 3) * 8] = av;
    }

    for (int nt = 0; nt < 3; ++nt) {
        #pragma unroll
        for (int p = 0; p < 4; ++p)
            *(u16x8*)&Bs[sc8 >> 2][srow + p * 32][(sc8 & 3) * 8] = wv[p];
        __syncthreads();
        if (nt < 2) {
            #pragma unroll
            for (int p = 0; p < 4; ++p)
                wv[p] = *(const u16x8*)&W[(size_t)((nt + 1) * 128 + srow + p * 32) * 128 + sc8 * 8];
        }
        f32x4 acc[4] = {};
        #pragma unroll
        for (int kc = 0; kc < 4; ++kc) {
            s16x8 af = __builtin_bit_cast(s16x8,
                *(const u16x8*)&As[kc][wm * 16 + c16][g4 * 8]);
            #pragma unroll
            for (int ni = 0; ni < 4; ++ni) {
                s16x8 bf = __builtin_bit_cast(s16x8,
                    *(const u16x8*)&Bs[kc][wn * 64 + ni * 16 + c16][g4 * 8]);
                acc[ni] = mfma16(af, bf, acc[ni]);
            }
        }
        #pragma unroll
        for (int r = 0; r < 4; ++r) {
            int m = m0 + wm * 16 + g4 * 4 + r;
            #pragma unroll
            for (int ni = 0; ni < 4; ++ni) {
                int col = nt * 128 + wn * 64 + ni * 16 + c16;
                float v = acc[ni][r] + bias[col] * (col < 128 ? QSCALE : 1.f);
                outp[(size_t)m * 384 + col] = f2bf(v);
            }
        }
        if (nt < 2) __syncthreads();
    }
}

// ---- proj GEMM + residual scatter -> bf16 R + fused LN2 -> bf16 ln_out ----
__global__ __launch_bounds__(512, 6) void proj_ln(
    const u16* __restrict__ A, const u16* __restrict__ W,
    const float* __restrict__ bias, u16* __restrict__ outp,
    const float* __restrict__ resid,
    const float* __restrict__ lng, const float* __restrict__ lnb,
    u16* __restrict__ ln_out)
{
    __shared__ u16 As[4][64][32];
    __shared__ u16 Bs[4][128][32];
    __shared__ float lnred[2][4][16][2];

    int tid = threadIdx.x, w = tid >> 6, l = tid & 63;
    int c16 = l & 15, g4 = l >> 4;
    int m0 = blockIdx.x * 64;
    int wm = w & 3, wn = w >> 2;

    #pragma unroll
    for (int p = 0; p < 2; ++p) {
        int e = tid + p * 512, row = e >> 4, c8 = e & 15;
        u16x8 v = *(const u16x8*)&A[(size_t)(m0 + row) * 128 + c8 * 8];
        *(u16x8*)&As[c8 >> 2][row][(c8 & 3) * 8] = v;
    }
    #pragma unroll
    for (int p = 0; p < 4; ++p) {
        int e = tid + p * 512, row = e >> 4, c8 = e & 15;
        u16x8 v = *(const u16x8*)&W[(size_t)row * 128 + c8 * 8];
        *(u16x8*)&Bs[c8 >> 2][row][(c8 & 3) * 8] = v;
    }
    __syncthreads();

    f32x4 acc[4] = {};
    #pragma unroll
    for (int kc = 0; kc < 4; ++kc) {
        s16x8 af = __builtin_bit_cast(s16x8,
            *(const u16x8*)&As[kc][wm * 16 + c16][g4 * 8]);
        #pragma unroll
        for (int ni = 0; ni < 4; ++ni) {
            s16x8 bf = __builtin_bit_cast(s16x8,
                *(const u16x8*)&Bs[kc][wn * 64 + ni * 16 + c16][g4 * 8]);
            acc[ni] = mfma16(af, bf, acc[ni]);
        }
    }

    float psum[4], psq[4];
    int dstl[4];
    #pragma unroll
    for (int r = 0; r < 4; ++r) {
        int m = m0 + wm * 16 + g4 * 4 + r;
        int dst = src_index(m);
        dstl[r] = dst;
        float s = 0.f, q = 0.f;
        #pragma unroll
        for (int ni = 0; ni < 4; ++ni) {
            int col = wn * 64 + ni * 16 + c16;
            float v = acc[ni][r] + bias[col] + resid[(size_t)dst * CH + col];
            acc[ni][r] = v;
            s += v; q += v * v;
        }
        psum[r] = s; psq[r] = q;
    }
    #pragma unroll
    for (int o = 1; o <= 8; o <<= 1)
        #pragma unroll
        for (int r = 0; r < 4; ++r) {
            psum[r] += __shfl_xor(psum[r], o);
            psq[r]  += __shfl_xor(psq[r], o);
        }
    if (c16 == 0) {
        #pragma unroll
        for (int r = 0; r < 4; ++r) {
            int rl = g4 * 4 + r;
            lnred[wn][wm][rl][0] = psum[r];
            lnred[wn][wm][rl][1] = psq[r];
        }
    }
    __syncthreads();
    float gl[4], bl[4];
    #pragma unroll
    for (int ni = 0; ni < 4; ++ni) {
        int col = wn * 64 + ni * 16 + c16;
        gl[ni] = lng[col]; bl[ni] = lnb[col];
    }
    #pragma unroll
    for (int r = 0; r < 4; ++r) {
        int rl = g4 * 4 + r;
        float s = lnred[0][wm][rl][0] + lnred[1][wm][rl][0];
        float q = lnred[0][wm][rl][1] + lnred[1][wm][rl][1];
        float mean = s * (1.f / CH);
        float var  = q * (1.f / CH) - mean * mean;
        float rstd = rsqrtf(var + LNEPS);
        int dst = dstl[r];
        #pragma unroll
        for (int ni = 0; ni < 4; ++ni) {
            int col = wn * 64 + ni * 16 + c16;
            float v = acc[ni][r];
            outp[(size_t)dst * CH + col] = f2bf(v);
            ln_out[(size_t)dst * CH + col] = f2bf((v - mean) * rstd * gl[ni] + bl[ni]);
        }
    }
}

// ---- fused MLP with register-prefetched weights ----
__global__ __launch_bounds__(512, 2) void mlp_fused(
    const u16* __restrict__ A, const u16* __restrict__ W1,
    const float* __restrict__ b1, const u16* __restrict__ W2,
    const float* __restrict__ b2, const u16* __restrict__ residb,
    float* __restrict__ outp)
{
    __shared__ u16 As[4][64][32];
    __shared__ u16 Bs[4][128][32];
    __shared__ u16 Hs[4][64][40];

    int tid = threadIdx.x, w = tid >> 6, l = tid & 63;
    int c16 = l & 15, g4 = l >> 4;
    int m0 = blockIdx.x * 64;
    int wm = w & 3, wn = w >> 2;
    int srow = tid >> 4, sc8 = tid & 15;

    u16x8 wv[4];
    #pragma unroll
    for (int p = 0; p < 4; ++p)
        wv[p] = *(const u16x8*)&W1[(size_t)(srow + p * 32) * 128 + sc8 * 8];
    #pragma unroll
    for (int p = 0; p < 2; ++p) {
        int row = srow + p * 32;
        u16x8 v = *(const u16x8*)&A[(size_t)(m0 + row) * 128 + sc8 * 8];
        *(u16x8*)&As[sc8 >> 2][row][(sc8 & 3) * 8] = v;
    }

    f32x4 acc2[4] = {};
    for (int ch = 0; ch < 4; ++ch) {
        #pragma unroll
        for (int p = 0; p < 4; ++p)
            *(u16x8*)&Bs[sc8 >> 2][srow + p * 32][(sc8 & 3) * 8] = wv[p];
        __syncthreads();

        u16x8 wv2[4];
        #pragma unroll
        for (int p = 0; p < 4; ++p)
            wv2[p] = *(const u16x8*)&W2[(size_t)(srow + p * 32) * 512 + ch * 128 + sc8 * 8];

        f32x4 hacc[4] = {};
        #pragma unroll
        for (int kc = 0; kc < 4; ++kc) {
            s16x8 af = __builtin_bit_cast(s16x8,
                *(const u16x8*)&As[kc][wm * 16 + c16][g4 * 8]);
            #pragma unroll
            for (int ni = 0; ni < 4; ++ni) {
                s16x8 bf = __builtin_bit_cast(s16x8,
                    *(const u16x8*)&Bs[kc][wn * 64 + ni * 16 + c16][g4 * 8]);
                hacc[ni] = mfma16(af, bf, hacc[ni]);
            }
        }
        #pragma unroll
        for (int r = 0; r < 4; ++r) {
            int row = wm * 16 + g4 * 4 + r;
            #pragma unroll
            for (int ni = 0; ni < 4; ++ni) {
                int col = wn * 64 + ni * 16 + c16;
                float v = hacc[ni][r] + b1[ch * 128 + col];
                v = 0.5f * v * (1.f + erff(v * 0.70710678118654752f));
                Hs[col >> 5][row][col & 31] = f2bf(v);
            }
        }
        __syncthreads();

        #pragma unroll
        for (int p = 0; p < 4; ++p)
            *(u16x8*)&Bs[sc8 >> 2][srow + p * 32][(sc8 & 3) * 8] = wv2[p];
        __syncthreads();

        if (ch < 3) {
            #pragma unroll
            for (int p = 0; p < 4; ++p)
                wv[p] = *(const u16x8*)&W1[(size_t)((ch + 1) * 128 + srow + p * 32) * 128 + sc8 * 8];
        }

        #pragma unroll
        for (int kc = 0; kc < 4; ++kc) {
            s16x8 af = __builtin_bit_cast(s16x8,
                *(const u16x8*)&Hs[kc][wm * 16 + c16][g4 * 8]);
            #pragma unroll
            for (int ni = 0; ni < 4; ++ni) {
                s16x8 bf = __builtin_bit_cast(s16x8,
                    *(const u16x8*)&Bs[kc][wn * 64 + ni * 16 + c16][g4 * 8]);
                acc2[ni] = mfma16(af, bf, acc2[ni]);
            }
        }
        if (ch < 3) __syncthreads();
    }

    #pragma unroll
    for (int r = 0; r < 4; ++r) {
        int m = m0 + wm * 16 + g4 * 4 + r;
        #pragma unroll
        for (int ni = 0; ni < 4; ++ni) {
            int col = wn * 64 + ni * 16 + c16;
            float v = acc2[ni][r] + b2[col];
            outp[(size_t)m * CH + col] = v + bf2f(residb[(size_t)m * CH + col]);
        }
    }
}

// ---- bias+mask table, f32, MFMA C-fragment layout: [hw][t][nt=26][lane][r] ----
__global__ __launch_bounds__(64) void bias_k(
    const float* __restrict__ rpb, float* __restrict__ biasT2)
{
    int nt = blockIdx.x;
    int t  = blockIdx.y;
    int hw = blockIdx.z;
    int l  = threadIdx.x;
    int head = hw >> 2, wt = hw & 3;
    int bh7 = wt >> 1, bw7 = wt & 1;
    int j = nt * 16 + (l & 15);
    int rb = t * 16 + (l >> 4) * 4;
    f32x4 outv;
    #pragma unroll
    for (int r = 0; r < 4; ++r) {
        int i = rb + r; if (i > NTOK - 1) i = NTOK - 1;
        float v;
        if (j >= NTOK) v = -100.f;
        else {
            int di = i / 49, ri = i - di * 49, hi = ri / 7, wi = ri - hi * 7;
            int dj = j / 49, rj = j - dj * 49, hj = rj / 7, wj = rj - hj * 7;
            int bidx = (di - dj + 7) * 169 + (hi - hj + 6) * 13 + (wi - wj + 6);
            v = rpb[bidx * NHEADS + head];
            int regi = (bh7 ? (hi < 4 ? 1 : 2) : 0) * 3 + (bw7 ? (wi < 4 ? 1 : 2) : 0);
            int regj = (bh7 ? (hj < 4 ? 1 : 2) : 0) * 3 + (bw7 ? (wj < 4 ? 1 : 2) : 0);
            if (regi != regj) v -= 100.f;
        }
        outv[r] = v;
    }
    *(f32x4*)&biasT2[((((size_t)hw * 25 + t) * 26 + nt) << 8) + (l << 2)] = outv;
}

// ---- flash-strip MFMA attention, 8 waves, 3-tile interleave + wave-0 4th tile ----
__global__ __launch_bounds__(512, 4) void attn_mfma(
    const u16* __restrict__ Qb, const float* __restrict__ biasT2,
    u16* __restrict__ O)
{
    __shared__ u16 Vt[32][420];         // 26880 B, cols 400..415 zero
    __shared__ u16 Pst[8][3][16][40];   // 30720 B
    __shared__ u16 PstD[16][40];        // 1280 B (wave 0's 4th tile)

    int bid = blockIdx.x;
    int win = bid >> 2, head = bid & 3;
    int tid = threadIdx.x, w = tid >> 6, l = tid & 63;
    int c16 = l & 15, g4 = l >> 4;

    const size_t qbase = (size_t)win * NTOK * 384;
    for (int e = tid; e < 1600; e += 512) {
        int j = e >> 2, d0 = (e & 3) * 8;
        u16x8 vv = {0, 0, 0, 0, 0, 0, 0, 0};
        if (j < NTOK)
            vv = *(const u16x8*)&Qb[qbase + (size_t)j * 384 + 256 + head * 32 + d0];
        #pragma unroll
        for (int i = 0; i < 8; ++i) Vt[d0 + i][j] = vv[i];
    }
    if (tid < 32 * 16) Vt[tid >> 4][400 + (tid & 15)] = 0;
    __syncthreads();

    int wIdx = win & 63;
    int wt = (((wIdx >> 3) == 7) ? 2 : 0) + (((wIdx & 7) == 7) ? 1 : 0);
    const float* bt = biasT2 + (((size_t)(head * 4 + wt) * 25 * 26) << 8) + (l << 2);
    const u16* kroot = Qb + qbase + 128 + head * 32 + g4 * 8;
    u16 (*myPA)[40] = Pst[w][0];
    u16 (*myPB)[40] = Pst[w][1];
    u16 (*myPC)[40] = Pst[w][2];
    bool hasD = (w == 0);

    int tA = w, tB = w + 8, tC = w + 16;
    s16x8 qfragA = __builtin_bit_cast(s16x8,
        *(const u16x8*)&Qb[qbase + (size_t)(tA * 16 + c16) * 384 + head * 32 + g4 * 8]);
    s16x8 qfragB = __builtin_bit_cast(s16x8,
        *(const u16x8*)&Qb[qbase + (size_t)(tB * 16 + c16) * 384 + head * 32 + g4 * 8]);
    s16x8 qfragC = __builtin_bit_cast(s16x8,
        *(const u16x8*)&Qb[qbase + (size_t)(tC * 16 + c16) * 384 + head * 32 + g4 * 8]);
    const float* bttA = bt + (((size_t)tA * 26) << 8);
    const float* bttB = bt + (((size_t)tB * 26) << 8);
    const float* bttC = bt + (((size_t)tC * 26) << 8);
    int qrD = 384 + c16; if (qrD > NTOK - 1) qrD = NTOK - 1;
    s16x8 qfragD = __builtin_bit_cast(s16x8,
        *(const u16x8*)&Qb[qbase + (size_t)qrD * 384 + head * 32 + g4 * 8]);
    const float* bttD = bt + (((size_t)24 * 26) << 8);

    float l4A[4] = {0.f,0.f,0.f,0.f}, l4B[4] = {0.f,0.f,0.f,0.f};
    float l4C[4] = {0.f,0.f,0.f,0.f}, l4D[4] = {0.f,0.f,0.f,0.f};
    f32x4 oaccA0 = {0.f,0.f,0.f,0.f}, oaccA1 = {0.f,0.f,0.f,0.f};
    f32x4 oaccB0 = {0.f,0.f,0.f,0.f}, oaccB1 = {0.f,0.f,0.f,0.f};
    f32x4 oaccC0 = {0.f,0.f,0.f,0.f}, oaccC1 = {0.f,0.f,0.f,0.f};
    f32x4 oaccD0 = {0.f,0.f,0.f,0.f}, oaccD1 = {0.f,0.f,0.f,0.f};

    for (int jb = 0; jb < 13; ++jb) {
        int kr0 = jb * 32 + c16;      if (kr0 > NTOK - 1) kr0 = NTOK - 1;
        int kr1 = jb * 32 + 16 + c16; if (kr1 > NTOK - 1) kr1 = NTOK - 1;
        s16x8 kf0 = __builtin_bit_cast(s16x8, *(const u16x8*)&kroot[(size_t)kr0 * 384]);
        s16x8 kf1 = __builtin_bit_cast(s16x8, *(const u16x8*)&kroot[(size_t)kr1 * 384]);
        f32x4 sA0 = mfma16(qfragA, kf0, *(const f32x4*)(bttA + (((size_t)(jb*2+0)) << 8)));
        f32x4 sA1 = mfma16(qfragA, kf1, *(const f32x4*)(bttA + (((size_t)(jb*2+1)) << 8)));
        f32x4 sB0 = mfma16(qfragB, kf0, *(const f32x4*)(bttB + (((size_t)(jb*2+0)) << 8)));
        f32x4 sB1 = mfma16(qfragB, kf1, *(const f32x4*)(bttB + (((size_t)(jb*2+1)) << 8)));
        f32x4 sC0 = mfma16(qfragC, kf0, *(const f32x4*)(bttC + (((size_t)(jb*2+0)) << 8)));
        f32x4 sC1 = mfma16(qfragC, kf1, *(const f32x4*)(bttC + (((size_t)(jb*2+1)) << 8)));
        #pragma unroll
        for (int r = 0; r < 4; ++r) {
            float p0 = exp2f(sA0[r] * 1.44269504f);
            float p1 = exp2f(sA1[r] * 1.44269504f);
            l4A[r] += p0 + p1;
            myPA[g4 * 4 + r][c16]      = f2bf(p0);
            myPA[g4 * 4 + r][16 + c16] = f2bf(p1);
        }
        #pragma unroll
        for (int r = 0; r < 4; ++r) {
            float p0 = exp2f(sB0[r] * 1.44269504f);
            float p1 = exp2f(sB1[r] * 1.44269504f);
            l4B[r] += p0 + p1;
            myPB[g4 * 4 + r][c16]      = f2bf(p0);
            myPB[g4 * 4 + r][16 + c16] = f2bf(p1);
        }
        #pragma unroll
        for (int r = 0; r < 4; ++r) {
            float p0 = exp2f(sC0[r] * 1.44269504f);
            float p1 = exp2f(sC1[r] * 1.44269504f);
            l4C[r] += p0 + p1;
            myPC[g4 * 4 + r][c16]      = f2bf(p0);
            myPC[g4 * 4 + r][16 + c16] = f2bf(p1);
        }
        if (hasD) {
            f32x4 sD0 = mfma16(qfragD, kf0, *(const f32x4*)(bttD + (((size_t)(jb*2+0)) << 8)));
            f32x4 sD1 = mfma16(qfragD, kf1, *(const f32x4*)(bttD + (((size_t)(jb*2+1)) << 8)));
            #pragma unroll
            for (int r = 0; r < 4; ++r) {
                float p0 = exp2f(sD0[r] * 1.44269504f);
                float p1 = exp2f(sD1[r] * 1.44269504f);
                l4D[r] += p0 + p1;
                PstD[g4 * 4 + r][c16]      = f2bf(p0);
                PstD[g4 * 4 + r][16 + c16] = f2bf(p1);
            }
        }
        s16x8 paA = __builtin_bit_cast(s16x8, *(const u16x8*)&myPA[c16][g4 * 8]);
        s16x8 paB = __builtin_bit_cast(s16x8, *(const u16x8*)&myPB[c16][g4 * 8]);
        s16x8 paC = __builtin_bit_cast(s16x8, *(const u16x8*)&myPC[c16][g4 * 8]);
        s16x8 vb0 = __builtin_bit_cast(s16x8, *(const u16x8*)&Vt[c16][jb * 32 + g4 * 8]);
        s16x8 vb1 = __builtin_bit_cast(s16x8, *(const u16x8*)&Vt[16 + c16][jb * 32 + g4 * 8]);
        oaccA0 = mfma16(paA, vb0, oaccA0);
        oaccA1 = mfma16(paA, vb1, oaccA1);
        oaccB0 = mfma16(paB, vb0, oaccB0);
        oaccB1 = mfma16(paB, vb1, oaccB1);
        oaccC0 = mfma16(paC, vb0, oaccC0);
        oaccC1 = mfma16(paC, vb1, oaccC1);
        if (hasD) {
            s16x8 paD = __builtin_bit_cast(s16x8, *(const u16x8*)&PstD[c16][g4 * 8]);
            oaccD0 = mfma16(paD, vb0, oaccD0);
            oaccD1 = mfma16(paD, vb1, oaccD1);
        }
    }

    #pragma unroll
    for (int r = 0; r < 4; ++r) {
        #pragma unroll
        for (int o = 1; o <= 8; o <<= 1) {
            l4A[r] += __shfl_xor(l4A[r], o);
            l4B[r] += __shfl_xor(l4B[r], o);
            l4C[r] += __shfl_xor(l4C[r], o);
        }
        l4A[r] = 1.f / l4A[r];
        l4B[r] = 1.f / l4B[r];
        l4C[r] = 1.f / l4C[r];
    }
    #pragma unroll
    for (int r = 0; r < 4; ++r) {
        int qA = tA * 16 + g4 * 4 + r;
        int qB = tB * 16 + g4 * 4 + r;
        int qC = tC * 16 + g4 * 4 + r;
        size_t oA = ((size_t)(win * NTOK + qA)) * CH + head * 32 + c16;
        size_t oB = ((size_t)(win * NTOK + qB)) * CH + head * 32 + c16;
        size_t oC = ((size_t)(win * NTOK + qC)) * CH + head * 32 + c16;
        O[oA]      = f2bf(oaccA0[r] * l4A[r]);
        O[oA + 16] = f2bf(oaccA1[r] * l4A[r]);
        O[oB]      = f2bf(oaccB0[r] * l4B[r]);
        O[oB + 16] = f2bf(oaccB1[r] * l4B[r]);
        O[oC]      = f2bf(oaccC0[r] * l4C[r]);
        O[oC + 16] = f2bf(oaccC1[r] * l4C[r]);
    }
    if (hasD) {
        #pragma unroll
        for (int r = 0; r < 4; ++r) {
            #pragma unroll
            for (int o = 1; o <= 8; o <<= 1)
                l4D[r] += __shfl_xor(l4D[r], o);
            l4D[r] = 1.f / l4D[r];
        }
        #pragma unroll
        for (int r = 0; r < 4; ++r) {
            int qD = 384 + g4 * 4 + r;
            if (qD < NTOK) {
                size_t oD = ((size_t)(win * NTOK + qD)) * CH + head * 32 + c16;
                O[oD]      = f2bf(oaccD0[r] * l4D[r]);
                O[oD + 16] = f2bf(oaccD1[r] * l4D[r]);
            }
        }
    }
}

extern "C" void kernel_launch(void* const* d_in, const int* in_sizes, int n_in,
                              void* d_out, int out_size, void* d_ws, size_t ws_size,
                              hipStream_t stream) {
    const float* x      = (const float*)d_in[0];
    const float* n1g    = (const float*)d_in[1];
    const float* n1b    = (const float*)d_in[2];
    const float* qkv_w  = (const float*)d_in[3];
    const float* qkv_b  = (const float*)d_in[4];
    const float* proj_w = (const float*)d_in[5];
    const float* proj_b = (const float*)d_in[6];
    const float* rpb    = (const float*)d_in[7];
    const float* n2g    = (const float*)d_in[8];
    const float* n2b    = (const float*)d_in[9];
    const float* fc1_w  = (const float*)d_in[10];
    const float* fc1_b  = (const float*)d_in[11];
    const float* fc2_w  = (const float*)d_in[12];
    const float* fc2_b  = (const float*)d_in[13];
    float* out = (float*)d_out;

    char* ws = (char*)d_ws;
    size_t off = 0;
    u16* A_bf  = (u16*)(ws + off);  off += (size_t)TOK * 128 * 2;   // LN2 out / biasT2 overlay
    u16* Qb_bf = (u16*)(ws + off);  off += (size_t)TOK * 384 * 2;
    u16* O_bf  = (u16*)(ws + off);  off += (size_t)TOK * 128 * 2;
    u16* R_bf  = (u16*)(ws + off);  off += (size_t)TOK * 128 * 2;   // bf16 residual trunk
    u16* qkvT  = (u16*)(ws + off);  off += 384 * 128 * 2;
    u16* projT = (u16*)(ws + off);  off += 128 * 128 * 2;
    u16* fc1T  = (u16*)(ws + off);  off += 512 * 128 * 2;
    u16* fc2T  = (u16*)(ws + off);  off += 128 * 512 * 2;
    float* biasT2 = (float*)A_bf;   // overlay; dead once proj's LN2 rewrites A_bf

    // 0. all weight transposes (+bf16), one launch; QSCALE folded into Wq
    hipLaunchKernelGGL(convT_all, dim3(16, 16, 4), dim3(256), 0, stream,
                       qkv_w, proj_w, fc1_w, fc2_w, qkvT, projT, fc1T, fc2T);
    // 0b. bias+mask table (overlay in A_bf)
    hipLaunchKernelGGL(bias_k, dim3(26, 25, 16), dim3(64), 0, stream, rpb, biasT2);
    // 1. fused LN1 + shift + qkv GEMM (single pass over x, 3 weight tiles)
    hipLaunchKernelGGL(qkv_ln, dim3(TOK/64), dim3(512), 0, stream,
                       x, qkvT, qkv_b, Qb_bf, n1g, n1b);
    // 2. flash attention, 3-tile interleave + wave-0 4th tile -> bf16
    hipLaunchKernelGGL(attn_mfma, dim3(NWIN * NHEADS), dim3(512), 0, stream,
                       Qb_bf, biasT2, O_bf);
    // 3. proj GEMM + unshift + residual -> bf16 R, fused LN2 -> bf16 A_bf
    hipLaunchKernelGGL(proj_ln, dim3(TOK/64), dim3(512), 0, stream,
                       O_bf, projT, proj_b, R_bf, x, n2g, n2b, A_bf);
    // 4. fused MLP (prefetched): fc1 + GELU + fc2 + residual -> f32 out
    hipLaunchKernelGGL(mlp_fused, dim3(TOK/64), dim3(512), 0, stream,
                       A_bf, fc1T, fc1_b, fc2T, fc2_b, R_bf, out);
}

// Round 26
// 143.227 us; speedup vs baseline: 1.0024x; 1.0024x over previous
//
#include <hip/hip_runtime.h>
#include <math.h>

// ---- problem constants ----
#define TOK    50176      // 2*8*56*56 tokens
#define CH     128
#define NWIN   128        // B * 64 windows
#define NTOK   392        // 8*7*7 tokens per window
#define NHEADS 4
#define QSCALE 0.17677669529663687f   // 32^-0.5
#define LNEPS  1e-3f

typedef unsigned short u16;
typedef unsigned int   u32;
typedef u16   u16x4  __attribute__((ext_vector_type(4)));
typedef u16   u16x8  __attribute__((ext_vector_type(8)));
typedef short s16x8  __attribute__((ext_vector_type(8)));
typedef float f32x4  __attribute__((ext_vector_type(4)));

__device__ __forceinline__ float bf2f(u16 u) {
    return __uint_as_float(((u32)u) << 16);
}
__device__ __forceinline__ u16 f2bf(float f) {
    u32 u = __float_as_uint(f);
    return (u16)((u + 0x7fffu + ((u >> 16) & 1u)) >> 16);
}
__device__ __forceinline__ f32x4 mfma16(s16x8 a, s16x8 b, f32x4 c) {
    return __builtin_amdgcn_mfma_f32_16x16x32_bf16(a, b, c, 0, 0, 0);
}

// token m in window layout -> flat token index in original layout (+3 roll)
__device__ __forceinline__ int src_index(int m) {
    int b = m / NTOK, t = m - b * NTOK;
    int batch = b >> 6, wIdx = b & 63;
    int bh = wIdx >> 3, bw = wIdx & 7;
    int d = t / 49, rem = t - d * 49;
    int h7 = rem / 7, w7 = rem - h7 * 7;
    int h = bh * 7 + h7 + 3; if (h >= 56) h -= 56;
    int w = bw * 7 + w7 + 3; if (w >= 56) w -= 56;
    return ((batch * 8 + d) * 56 + h) * 56 + w;
}

// ---- batched weight transpose + f32->bf16: all 4 weights, one launch ----
__global__ __launch_bounds__(256) void convT_all(
    const float* __restrict__ qkv_w, const float* __restrict__ proj_w,
    const float* __restrict__ fc1_w, const float* __restrict__ fc2_w,
    u16* __restrict__ qkvT, u16* __restrict__ projT,
    u16* __restrict__ fc1T, u16* __restrict__ fc2T)
{
    const float* src; u16* dst; int K, N, scaleN;
    switch (blockIdx.z) {
    case 0:  src = qkv_w;  dst = qkvT;  K = 128; N = 384; scaleN = 128; break;
    case 1:  src = proj_w; dst = projT; K = 128; N = 128; scaleN = 0;   break;
    case 2:  src = fc1_w;  dst = fc1T;  K = 128; N = 512; scaleN = 0;   break;
    default: src = fc2_w;  dst = fc2T;  K = 512; N = 128; scaleN = 0;   break;
    }
    int n0 = blockIdx.x * 32, k0 = blockIdx.y * 32;
    if (n0 >= N || k0 >= K) return;
    __shared__ float t[32][33];
    int tx = threadIdx.x & 31, ty = threadIdx.x >> 5;   // ty 0..7
    #pragma unroll
    for (int r = 0; r < 4; ++r)
        t[ty + r * 8][tx] = src[(size_t)(k0 + ty + r * 8) * N + n0 + tx];
    __syncthreads();
    #pragma unroll
    for (int r = 0; r < 4; ++r) {
        int n = n0 + ty + r * 8;
        float sc = (n < scaleN) ? QSCALE : 1.f;
        dst[(size_t)n * K + k0 + tx] = f2bf(t[tx][ty + r * 8] * sc);
    }
}

// ---- fused LN1 + qkv GEMM, one block per 64-token tile, loops 3 n-tiles ----
__global__ __launch_bounds__(512, 6) void qkv_ln(
    const float* __restrict__ x, const u16* __restrict__ W,
    const float* __restrict__ bias, u16* __restrict__ outp,
    const float* __restrict__ lng, const float* __restrict__ lnb)
{
    __shared__ u16 As[4][64][32];    // 16 KB
    __shared__ u16 Bs[4][128][32];   // 32 KB

    int tid = threadIdx.x, l = tid & 63;
    int c16 = l & 15, g4 = l >> 4;
    int m0 = blockIdx.x * 64;
    int w = tid >> 6, wm = w & 3, wn = w >> 2;
    int srow = tid >> 4, sc8 = tid & 15;

    u16x8 wv[4];
    #pragma unroll
    for (int p = 0; p < 4; ++p)
        wv[p] = *(const u16x8*)&W[(size_t)(srow + p * 32) * 128 + sc8 * 8];

    #pragma unroll
    for (int p = 0; p < 2; ++p) {
        int row = srow + p * 32;
        int src = src_index(m0 + row);
        f32x4 x0 = *(const f32x4*)&x[(size_t)src * CH + sc8 * 8];
        f32x4 x1 = *(const f32x4*)&x[(size_t)src * CH + sc8 * 8 + 4];
        float s = ((x0[0] + x0[1]) + (x0[2] + x0[3]))
                + ((x1[0] + x1[1]) + (x1[2] + x1[3]));
        float q = ((x0[0]*x0[0] + x0[1]*x0[1]) + (x0[2]*x0[2] + x0[3]*x0[3]))
                + ((x1[0]*x1[0] + x1[1]*x1[1]) + (x1[2]*x1[2] + x1[3]*x1[3]));
        #pragma unroll
        for (int o = 1; o <= 8; o <<= 1) {
            s += __shfl_xor(s, o);
            q += __shfl_xor(q, o);
        }
        float mean = s * (1.f / CH);
        float var  = q * (1.f / CH) - mean * mean;
        float rstd = rsqrtf(var + LNEPS);
        u16x8 av;
        #pragma unroll
        for (int i = 0; i < 4; ++i)
            av[i] = f2bf((x0[i] - mean) * rstd * lng[sc8 * 8 + i] + lnb[sc8 * 8 + i]);
        #pragma unroll
        for (int i = 0; i < 4; ++i)
            av[4 + i] = f2bf((x1[i] - mean) * rstd * lng[sc8 * 8 + 4 + i] + lnb[sc8 * 8 + 4 + i]);
        *(u16x8*)&As[sc8 >> 2][row][(sc8 & 3) * 8] = av;
    }

    for (int nt = 0; nt < 3; ++nt) {
        #pragma unroll
        for (int p = 0; p < 4; ++p)
            *(u16x8*)&Bs[sc8 >> 2][srow + p * 32][(sc8 & 3) * 8] = wv[p];
        __syncthreads();
        if (nt < 2) {
            #pragma unroll
            for (int p = 0; p < 4; ++p)
                wv[p] = *(const u16x8*)&W[(size_t)((nt + 1) * 128 + srow + p * 32) * 128 + sc8 * 8];
        }
        f32x4 acc[4] = {};
        #pragma unroll
        for (int kc = 0; kc < 4; ++kc) {
            s16x8 af = __builtin_bit_cast(s16x8,
                *(const u16x8*)&As[kc][wm * 16 + c16][g4 * 8]);
            #pragma unroll
            for (int ni = 0; ni < 4; ++ni) {
                s16x8 bf = __builtin_bit_cast(s16x8,
                    *(const u16x8*)&Bs[kc][wn * 64 + ni * 16 + c16][g4 * 8]);
                acc[ni] = mfma16(af, bf, acc[ni]);
            }
        }
        #pragma unroll
        for (int r = 0; r < 4; ++r) {
            int m = m0 + wm * 16 + g4 * 4 + r;
            #pragma unroll
            for (int ni = 0; ni < 4; ++ni) {
                int col = nt * 128 + wn * 64 + ni * 16 + c16;
                float v = acc[ni][r] + bias[col] * (col < 128 ? QSCALE : 1.f);
                outp[(size_t)m * 384 + col] = f2bf(v);
            }
        }
        if (nt < 2) __syncthreads();
    }
}

// ---- proj GEMM + residual scatter -> bf16 R + fused LN2 -> bf16 ln_out ----
__global__ __launch_bounds__(512, 6) void proj_ln(
    const u16* __restrict__ A, const u16* __restrict__ W,
    const float* __restrict__ bias, u16* __restrict__ outp,
    const float* __restrict__ resid,
    const float* __restrict__ lng, const float* __restrict__ lnb,
    u16* __restrict__ ln_out)
{
    __shared__ u16 As[4][64][32];
    __shared__ u16 Bs[4][128][32];
    __shared__ float lnred[2][4][16][2];

    int tid = threadIdx.x, w = tid >> 6, l = tid & 63;
    int c16 = l & 15, g4 = l >> 4;
    int m0 = blockIdx.x * 64;
    int wm = w & 3, wn = w >> 2;

    #pragma unroll
    for (int p = 0; p < 2; ++p) {
        int e = tid + p * 512, row = e >> 4, c8 = e & 15;
        u16x8 v = *(const u16x8*)&A[(size_t)(m0 + row) * 128 + c8 * 8];
        *(u16x8*)&As[c8 >> 2][row][(c8 & 3) * 8] = v;
    }
    #pragma unroll
    for (int p = 0; p < 4; ++p) {
        int e = tid + p * 512, row = e >> 4, c8 = e & 15;
        u16x8 v = *(const u16x8*)&W[(size_t)row * 128 + c8 * 8];
        *(u16x8*)&Bs[c8 >> 2][row][(c8 & 3) * 8] = v;
    }
    __syncthreads();

    f32x4 acc[4] = {};
    #pragma unroll
    for (int kc = 0; kc < 4; ++kc) {
        s16x8 af = __builtin_bit_cast(s16x8,
            *(const u16x8*)&As[kc][wm * 16 + c16][g4 * 8]);
        #pragma unroll
        for (int ni = 0; ni < 4; ++ni) {
            s16x8 bf = __builtin_bit_cast(s16x8,
                *(const u16x8*)&Bs[kc][wn * 64 + ni * 16 + c16][g4 * 8]);
            acc[ni] = mfma16(af, bf, acc[ni]);
        }
    }

    float psum[4], psq[4];
    int dstl[4];
    #pragma unroll
    for (int r = 0; r < 4; ++r) {
        int m = m0 + wm * 16 + g4 * 4 + r;
        int dst = src_index(m);
        dstl[r] = dst;
        float s = 0.f, q = 0.f;
        #pragma unroll
        for (int ni = 0; ni < 4; ++ni) {
            int col = wn * 64 + ni * 16 + c16;
            float v = acc[ni][r] + bias[col] + resid[(size_t)dst * CH + col];
            acc[ni][r] = v;
            s += v; q += v * v;
        }
        psum[r] = s; psq[r] = q;
    }
    #pragma unroll
    for (int o = 1; o <= 8; o <<= 1)
        #pragma unroll
        for (int r = 0; r < 4; ++r) {
            psum[r] += __shfl_xor(psum[r], o);
            psq[r]  += __shfl_xor(psq[r], o);
        }
    if (c16 == 0) {
        #pragma unroll
        for (int r = 0; r < 4; ++r) {
            int rl = g4 * 4 + r;
            lnred[wn][wm][rl][0] = psum[r];
            lnred[wn][wm][rl][1] = psq[r];
        }
    }
    __syncthreads();
    float gl[4], bl[4];
    #pragma unroll
    for (int ni = 0; ni < 4; ++ni) {
        int col = wn * 64 + ni * 16 + c16;
        gl[ni] = lng[col]; bl[ni] = lnb[col];
    }
    #pragma unroll
    for (int r = 0; r < 4; ++r) {
        int rl = g4 * 4 + r;
        float s = lnred[0][wm][rl][0] + lnred[1][wm][rl][0];
        float q = lnred[0][wm][rl][1] + lnred[1][wm][rl][1];
        float mean = s * (1.f / CH);
        float var  = q * (1.f / CH) - mean * mean;
        float rstd = rsqrtf(var + LNEPS);
        int dst = dstl[r];
        #pragma unroll
        for (int ni = 0; ni < 4; ++ni) {
            int col = wn * 64 + ni * 16 + c16;
            float v = acc[ni][r];
            outp[(size_t)dst * CH + col] = f2bf(v);
            ln_out[(size_t)dst * CH + col] = f2bf((v - mean) * rstd * gl[ni] + bl[ni]);
        }
    }
}

// ---- fused MLP with register-prefetched weights ----
__global__ __launch_bounds__(512, 2) void mlp_fused(
    const u16* __restrict__ A, const u16* __restrict__ W1,
    const float* __restrict__ b1, const u16* __restrict__ W2,
    const float* __restrict__ b2, const u16* __restrict__ residb,
    float* __restrict__ outp)
{
    __shared__ u16 As[4][64][32];
    __shared__ u16 Bs[4][128][32];
    __shared__ u16 Hs[4][64][40];

    int tid = threadIdx.x, w = tid >> 6, l = tid & 63;
    int c16 = l & 15, g4 = l >> 4;
    int m0 = blockIdx.x * 64;
    int wm = w & 3, wn = w >> 2;
    int srow = tid >> 4, sc8 = tid & 15;

    u16x8 wv[4];
    #pragma unroll
    for (int p = 0; p < 4; ++p)
        wv[p] = *(const u16x8*)&W1[(size_t)(srow + p * 32) * 128 + sc8 * 8];
    #pragma unroll
    for (int p = 0; p < 2; ++p) {
        int row = srow + p * 32;
        u16x8 v = *(const u16x8*)&A[(size_t)(m0 + row) * 128 + sc8 * 8];
        *(u16x8*)&As[sc8 >> 2][row][(sc8 & 3) * 8] = v;
    }

    f32x4 acc2[4] = {};
    for (int ch = 0; ch < 4; ++ch) {
        #pragma unroll
        for (int p = 0; p < 4; ++p)
            *(u16x8*)&Bs[sc8 >> 2][srow + p * 32][(sc8 & 3) * 8] = wv[p];
        __syncthreads();

        u16x8 wv2[4];
        #pragma unroll
        for (int p = 0; p < 4; ++p)
            wv2[p] = *(const u16x8*)&W2[(size_t)(srow + p * 32) * 512 + ch * 128 + sc8 * 8];

        f32x4 hacc[4] = {};
        #pragma unroll
        for (int kc = 0; kc < 4; ++kc) {
            s16x8 af = __builtin_bit_cast(s16x8,
                *(const u16x8*)&As[kc][wm * 16 + c16][g4 * 8]);
            #pragma unroll
            for (int ni = 0; ni < 4; ++ni) {
                s16x8 bf = __builtin_bit_cast(s16x8,
                    *(const u16x8*)&Bs[kc][wn * 64 + ni * 16 + c16][g4 * 8]);
                hacc[ni] = mfma16(af, bf, hacc[ni]);
            }
        }
        #pragma unroll
        for (int r = 0; r < 4; ++r) {
            int row = wm * 16 + g4 * 4 + r;
            #pragma unroll
            for (int ni = 0; ni < 4; ++ni) {
                int col = wn * 64 + ni * 16 + c16;
                float v = hacc[ni][r] + b1[ch * 128 + col];
                v = 0.5f * v * (1.f + erff(v * 0.70710678118654752f));
                Hs[col >> 5][row][col & 31] = f2bf(v);
            }
        }
        __syncthreads();

        #pragma unroll
        for (int p = 0; p < 4; ++p)
            *(u16x8*)&Bs[sc8 >> 2][srow + p * 32][(sc8 & 3) * 8] = wv2[p];
        __syncthreads();

        if (ch < 3) {
            #pragma unroll
            for (int p = 0; p < 4; ++p)
                wv[p] = *(const u16x8*)&W1[(size_t)((ch + 1) * 128 + srow + p * 32) * 128 + sc8 * 8];
        }

        #pragma unroll
        for (int kc = 0; kc < 4; ++kc) {
            s16x8 af = __builtin_bit_cast(s16x8,
                *(const u16x8*)&Hs[kc][wm * 16 + c16][g4 * 8]);
            #pragma unroll
            for (int ni = 0; ni < 4; ++ni) {
                s16x8 bf = __builtin_bit_cast(s16x8,
                    *(const u16x8*)&Bs[kc][wn * 64 + ni * 16 + c16][g4 * 8]);
                acc2[ni] = mfma16(af, bf, acc2[ni]);
            }
        }
        if (ch < 3) __syncthreads();
    }

    #pragma unroll
    for (int r = 0; r < 4; ++r) {
        int m = m0 + wm * 16 + g4 * 4 + r;
        #pragma unroll
        for (int ni = 0; ni < 4; ++ni) {
            int col = wn * 64 + ni * 16 + c16;
            float v = acc2[ni][r] + b2[col];
            outp[(size_t)m * CH + col] = v + bf2f(residb[(size_t)m * CH + col]);
        }
    }
}

// ---- bias+mask table, f32, MFMA C-fragment layout: [hw][t][nt=26][lane][r] ----
__global__ __launch_bounds__(64) void bias_k(
    const float* __restrict__ rpb, float* __restrict__ biasT2)
{
    int nt = blockIdx.x;
    int t  = blockIdx.y;
    int hw = blockIdx.z;
    int l  = threadIdx.x;
    int head = hw >> 2, wt = hw & 3;
    int bh7 = wt >> 1, bw7 = wt & 1;
    int j = nt * 16 + (l & 15);
    int rb = t * 16 + (l >> 4) * 4;
    f32x4 outv;
    #pragma unroll
    for (int r = 0; r < 4; ++r) {
        int i = rb + r; if (i > NTOK - 1) i = NTOK - 1;
        float v;
        if (j >= NTOK) v = -100.f;
        else {
            int di = i / 49, ri = i - di * 49, hi = ri / 7, wi = ri - hi * 7;
            int dj = j / 49, rj = j - dj * 49, hj = rj / 7, wj = rj - hj * 7;
            int bidx = (di - dj + 7) * 169 + (hi - hj + 6) * 13 + (wi - wj + 6);
            v = rpb[bidx * NHEADS + head];
            int regi = (bh7 ? (hi < 4 ? 1 : 2) : 0) * 3 + (bw7 ? (wi < 4 ? 1 : 2) : 0);
            int regj = (bh7 ? (hj < 4 ? 1 : 2) : 0) * 3 + (bw7 ? (wj < 4 ? 1 : 2) : 0);
            if (regi != regj) v -= 100.f;
        }
        outv[r] = v;
    }
    *(f32x4*)&biasT2[((((size_t)hw * 25 + t) * 26 + nt) << 8) + (l << 2)] = outv;
}

// ---- flash-strip MFMA attention, 8 waves, 3-tile interleave + wave-0 4th tile ----
__global__ __launch_bounds__(512, 4) void attn_mfma(
    const u16* __restrict__ Qb, const float* __restrict__ biasT2,
    u16* __restrict__ O)
{
    __shared__ u16 Vt[32][420];         // 26880 B, cols 400..415 zero
    __shared__ u16 Pst[8][3][16][40];   // 30720 B
    __shared__ u16 PstD[16][40];        // 1280 B (wave 0's 4th tile)

    int bid = blockIdx.x;
    int win = bid >> 2, head = bid & 3;
    int tid = threadIdx.x, w = tid >> 6, l = tid & 63;
    int c16 = l & 15, g4 = l >> 4;

    const size_t qbase = (size_t)win * NTOK * 384;
    for (int e = tid; e < 1600; e += 512) {
        int j = e >> 2, d0 = (e & 3) * 8;
        u16x8 vv = {0, 0, 0, 0, 0, 0, 0, 0};
        if (j < NTOK)
            vv = *(const u16x8*)&Qb[qbase + (size_t)j * 384 + 256 + head * 32 + d0];
        #pragma unroll
        for (int i = 0; i < 8; ++i) Vt[d0 + i][j] = vv[i];
    }
    if (tid < 32 * 16) Vt[tid >> 4][400 + (tid & 15)] = 0;
    __syncthreads();

    int wIdx = win & 63;
    int wt = (((wIdx >> 3) == 7) ? 2 : 0) + (((wIdx & 7) == 7) ? 1 : 0);
    const float* bt = biasT2 + (((size_t)(head * 4 + wt) * 25 * 26) << 8) + (l << 2);
    const u16* kroot = Qb + qbase + 128 + head * 32 + g4 * 8;
    u16 (*myPA)[40] = Pst[w][0];
    u16 (*myPB)[40] = Pst[w][1];
    u16 (*myPC)[40] = Pst[w][2];
    bool hasD = (w == 0);

    int tA = w, tB = w + 8, tC = w + 16;
    s16x8 qfragA = __builtin_bit_cast(s16x8,
        *(const u16x8*)&Qb[qbase + (size_t)(tA * 16 + c16) * 384 + head * 32 + g4 * 8]);
    s16x8 qfragB = __builtin_bit_cast(s16x8,
        *(const u16x8*)&Qb[qbase + (size_t)(tB * 16 + c16) * 384 + head * 32 + g4 * 8]);
    s16x8 qfragC = __builtin_bit_cast(s16x8,
        *(const u16x8*)&Qb[qbase + (size_t)(tC * 16 + c16) * 384 + head * 32 + g4 * 8]);
    const float* bttA = bt + (((size_t)tA * 26) << 8);
    const float* bttB = bt + (((size_t)tB * 26) << 8);
    const float* bttC = bt + (((size_t)tC * 26) << 8);
    int qrD = 384 + c16; if (qrD > NTOK - 1) qrD = NTOK - 1;
    s16x8 qfragD = __builtin_bit_cast(s16x8,
        *(const u16x8*)&Qb[qbase + (size_t)qrD * 384 + head * 32 + g4 * 8]);
    const float* bttD = bt + (((size_t)24 * 26) << 8);

    float l4A[4] = {0.f,0.f,0.f,0.f}, l4B[4] = {0.f,0.f,0.f,0.f};
    float l4C[4] = {0.f,0.f,0.f,0.f}, l4D[4] = {0.f,0.f,0.f,0.f};
    f32x4 oaccA0 = {0.f,0.f,0.f,0.f}, oaccA1 = {0.f,0.f,0.f,0.f};
    f32x4 oaccB0 = {0.f,0.f,0.f,0.f}, oaccB1 = {0.f,0.f,0.f,0.f};
    f32x4 oaccC0 = {0.f,0.f,0.f,0.f}, oaccC1 = {0.f,0.f,0.f,0.f};
    f32x4 oaccD0 = {0.f,0.f,0.f,0.f}, oaccD1 = {0.f,0.f,0.f,0.f};

    for (int jb = 0; jb < 13; ++jb) {
        int kr0 = jb * 32 + c16;      if (kr0 > NTOK - 1) kr0 = NTOK - 1;
        int kr1 = jb * 32 + 16 + c16; if (kr1 > NTOK - 1) kr1 = NTOK - 1;
        s16x8 kf0 = __builtin_bit_cast(s16x8, *(const u16x8*)&kroot[(size_t)kr0 * 384]);
        s16x8 kf1 = __builtin_bit_cast(s16x8, *(const u16x8*)&kroot[(size_t)kr1 * 384]);
        f32x4 sA0 = mfma16(qfragA, kf0, *(const f32x4*)(bttA + (((size_t)(jb*2+0)) << 8)));
        f32x4 sA1 = mfma16(qfragA, kf1, *(const f32x4*)(bttA + (((size_t)(jb*2+1)) << 8)));
        f32x4 sB0 = mfma16(qfragB, kf0, *(const f32x4*)(bttB + (((size_t)(jb*2+0)) << 8)));
        f32x4 sB1 = mfma16(qfragB, kf1, *(const f32x4*)(bttB + (((size_t)(jb*2+1)) << 8)));
        f32x4 sC0 = mfma16(qfragC, kf0, *(const f32x4*)(bttC + (((size_t)(jb*2+0)) << 8)));
        f32x4 sC1 = mfma16(qfragC, kf1, *(const f32x4*)(bttC + (((size_t)(jb*2+1)) << 8)));
        #pragma unroll
        for (int r = 0; r < 4; ++r) {
            float p0 = exp2f(sA0[r] * 1.44269504f);
            float p1 = exp2f(sA1[r] * 1.44269504f);
            l4A[r] += p0 + p1;
            myPA[g4 * 4 + r][c16]      = f2bf(p0);
            myPA[g4 * 4 + r][16 + c16] = f2bf(p1);
        }
        #pragma unroll
        for (int r = 0; r < 4; ++r) {
            float p0 = exp2f(sB0[r] * 1.44269504f);
            float p1 = exp2f(sB1[r] * 1.44269504f);
            l4B[r] += p0 + p1;
            myPB[g4 * 4 + r][c16]      = f2bf(p0);
            myPB[g4 * 4 + r][16 + c16] = f2bf(p1);
        }
        #pragma unroll
        for (int r = 0; r < 4; ++r) {
            float p0 = exp2f(sC0[r] * 1.44269504f);
            float p1 = exp2f(sC1[r] * 1.44269504f);
            l4C[r] += p0 + p1;
            myPC[g4 * 4 + r][c16]      = f2bf(p0);
            myPC[g4 * 4 + r][16 + c16] = f2bf(p1);
        }
        if (hasD) {
            f32x4 sD0 = mfma16(qfragD, kf0, *(const f32x4*)(bttD + (((size_t)(jb*2+0)) << 8)));
            f32x4 sD1 = mfma16(qfragD, kf1, *(const f32x4*)(bttD + (((size_t)(jb*2+1)) << 8)));
            #pragma unroll
            for (int r = 0; r < 4; ++r) {
                float p0 = exp2f(sD0[r] * 1.44269504f);
                float p1 = exp2f(sD1[r] * 1.44269504f);
                l4D[r] += p0 + p1;
                PstD[g4 * 4 + r][c16]      = f2bf(p0);
                PstD[g4 * 4 + r][16 + c16] = f2bf(p1);
            }
        }
        s16x8 paA = __builtin_bit_cast(s16x8, *(const u16x8*)&myPA[c16][g4 * 8]);
        s16x8 paB = __builtin_bit_cast(s16x8, *(const u16x8*)&myPB[c16][g4 * 8]);
        s16x8 paC = __builtin_bit_cast(s16x8, *(const u16x8*)&myPC[c16][g4 * 8]);
        s16x8 vb0 = __builtin_bit_cast(s16x8, *(const u16x8*)&Vt[c16][jb * 32 + g4 * 8]);
        s16x8 vb1 = __builtin_bit_cast(s16x8, *(const u16x8*)&Vt[16 + c16][jb * 32 + g4 * 8]);
        oaccA0 = mfma16(paA, vb0, oaccA0);
        oaccA1 = mfma16(paA, vb1, oaccA1);
        oaccB0 = mfma16(paB, vb0, oaccB0);
        oaccB1 = mfma16(paB, vb1, oaccB1);
        oaccC0 = mfma16(paC, vb0, oaccC0);
        oaccC1 = mfma16(paC, vb1, oaccC1);
        if (hasD) {
            s16x8 paD = __builtin_bit_cast(s16x8, *(const u16x8*)&PstD[c16][g4 * 8]);
            oaccD0 = mfma16(paD, vb0, oaccD0);
            oaccD1 = mfma16(paD, vb1, oaccD1);
        }
    }

    #pragma unroll
    for (int r = 0; r < 4; ++r) {
        #pragma unroll
        for (int o = 1; o <= 8; o <<= 1) {
            l4A[r] += __shfl_xor(l4A[r], o);
            l4B[r] += __shfl_xor(l4B[r], o);
            l4C[r] += __shfl_xor(l4C[r], o);
        }
        l4A[r] = 1.f / l4A[r];
        l4B[r] = 1.f / l4B[r];
        l4C[r] = 1.f / l4C[r];
    }
    #pragma unroll
    for (int r = 0; r < 4; ++r) {
        int qA = tA * 16 + g4 * 4 + r;
        int qB = tB * 16 + g4 * 4 + r;
        int qC = tC * 16 + g4 * 4 + r;
        size_t oA = ((size_t)(win * NTOK + qA)) * CH + head * 32 + c16;
        size_t oB = ((size_t)(win * NTOK + qB)) * CH + head * 32 + c16;
        size_t oC = ((size_t)(win * NTOK + qC)) * CH + head * 32 + c16;
        O[oA]      = f2bf(oaccA0[r] * l4A[r]);
        O[oA + 16] = f2bf(oaccA1[r] * l4A[r]);
        O[oB]      = f2bf(oaccB0[r] * l4B[r]);
        O[oB + 16] = f2bf(oaccB1[r] * l4B[r]);
        O[oC]      = f2bf(oaccC0[r] * l4C[r]);
        O[oC + 16] = f2bf(oaccC1[r] * l4C[r]);
    }
    if (hasD) {
        #pragma unroll
        for (int r = 0; r < 4; ++r) {
            #pragma unroll
            for (int o = 1; o <= 8; o <<= 1)
                l4D[r] += __shfl_xor(l4D[r], o);
            l4D[r] = 1.f / l4D[r];
        }
        #pragma unroll
        for (int r = 0; r < 4; ++r) {
            int qD = 384 + g4 * 4 + r;
            if (qD < NTOK) {
                size_t oD = ((size_t)(win * NTOK + qD)) * CH + head * 32 + c16;
                O[oD]      = f2bf(oaccD0[r] * l4D[r]);
                O[oD + 16] = f2bf(oaccD1[r] * l4D[r]);
            }
        }
    }
}

extern "C" void kernel_launch(void* const* d_in, const int* in_sizes, int n_in,
                              void* d_out, int out_size, void* d_ws, size_t ws_size,
                              hipStream_t stream) {
    const float* x      = (const float*)d_in[0];
    const float* n1g    = (const float*)d_in[1];
    const float* n1b    = (const float*)d_in[2];
    const float* qkv_w  = (const float*)d_in[3];
    const float* qkv_b  = (const float*)d_in[4];
    const float* proj_w = (const float*)d_in[5];
    const float* proj_b = (const float*)d_in[6];
    const float* rpb    = (const float*)d_in[7];
    const float* n2g    = (const float*)d_in[8];
    const float* n2b    = (const float*)d_in[9];
    const float* fc1_w  = (const float*)d_in[10];
    const float* fc1_b  = (const float*)d_in[11];
    const float* fc2_w  = (const float*)d_in[12];
    const float* fc2_b  = (const float*)d_in[13];
    float* out = (float*)d_out;

    char* ws = (char*)d_ws;
    size_t off = 0;
    u16* A_bf  = (u16*)(ws + off);  off += (size_t)TOK * 128 * 2;   // LN2 out / biasT2 overlay
    u16* Qb_bf = (u16*)(ws + off);  off += (size_t)TOK * 384 * 2;
    u16* O_bf  = (u16*)(ws + off);  off += (size_t)TOK * 128 * 2;
    u16* R_bf  = (u16*)(ws + off);  off += (size_t)TOK * 128 * 2;   // bf16 residual trunk
    u16* qkvT  = (u16*)(ws + off);  off += 384 * 128 * 2;
    u16* projT = (u16*)(ws + off);  off += 128 * 128 * 2;
    u16* fc1T  = (u16*)(ws + off);  off += 512 * 128 * 2;
    u16* fc2T  = (u16*)(ws + off);  off += 128 * 512 * 2;
    float* biasT2 = (float*)A_bf;   // overlay; dead once proj's LN2 rewrites A_bf

    // 0. all weight transposes (+bf16), one launch; QSCALE folded into Wq
    hipLaunchKernelGGL(convT_all, dim3(16, 16, 4), dim3(256), 0, stream,
                       qkv_w, proj_w, fc1_w, fc2_w, qkvT, projT, fc1T, fc2T);
    // 0b. bias+mask table (overlay in A_bf)
    hipLaunchKernelGGL(bias_k, dim3(26, 25, 16), dim3(64), 0, stream, rpb, biasT2);
    // 1. fused LN1 + shift + qkv GEMM (single pass over x, 3 weight tiles)
    hipLaunchKernelGGL(qkv_ln, dim3(TOK/64), dim3(512), 0, stream,
                       x, qkvT, qkv_b, Qb_bf, n1g, n1b);
    // 2. flash attention, 3-tile interleave + wave-0 4th tile -> bf16
    hipLaunchKernelGGL(attn_mfma, dim3(NWIN * NHEADS), dim3(512), 0, stream,
                       Qb_bf, biasT2, O_bf);
    // 3. proj GEMM + unshift + residual -> bf16 R, fused LN2 -> bf16 A_bf
    hipLaunchKernelGGL(proj_ln, dim3(TOK/64), dim3(512), 0, stream,
                       O_bf, projT, proj_b, R_bf, x, n2g, n2b, A_bf);
    // 4. fused MLP (prefetched): fc1 + GELU + fc2 + residual -> f32 out
    hipLaunchKernelGGL(mlp_fused, dim3(TOK/64), dim3(512), 0, stream,
                       A_bf, fc1T, fc1_b, fc2T, fc2_b, R_bf, out);
}